// Round 4
// baseline (302.235 us; speedup 1.0000x reference)
//
#include <hip/hip_runtime.h>
#include <stdint.h>

// DualModel3 R4: m97-style K-loop. global_load_lds DMA of fp32 tiles
// (consume-side cvt to bf16), single LDS buffer, 2-barrier loop, 4 blocks/CU
// for cross-block drain hiding (m114). R3 lesson: register prefetch is dead
// on arrival — compiler drains vmcnt(0) at every s_barrier.
//
// GEMM: M=256(batch) x N=17408(1024 fc cols + 16384 decoder cols) x K=2048.
// BM=64, BN=64, BK=64; grid 272 col-groups x 4 row-groups = 1088 blocks,
// XCD-swizzled so the 4 row-group siblings share one XCD's L2 (W1 -> HBM once).
// DMA slab = 1KB (64 lanes x 16B), slab stride 1040B (bank decorrelation).
//   A slab: 4 rows x 64k fp32 of x.        B fc slab: 4 rows x 64k of fcW.
//   B dec slab: one o: 64k x 4h fp32 of W1 (1KB contiguous global).
// mfma_f32_16x16x32_bf16, 4 waves x (2m x 2n). Decoder epilogue: bias +
// leaky-relu + W2-weighted H-reduce (__shfl_xor over 4 adjacent lanes),
// staged through LDS for full-line x2 stores (R3's 54MB write amplification).

typedef __bf16 bf16_t;
typedef __bf16 bf16x8 __attribute__((ext_vector_type(8)));
typedef float  f32x4  __attribute__((ext_vector_type(4)));

#define AS1 __attribute__((address_space(1)))
#define AS3 __attribute__((address_space(3)))
#define SLAB 1040

__device__ __forceinline__ void dma16(const float* g, AS3 char* lds_base) {
    // HW semantics: dest(lane) = lds_base + lane*16 ; g is per-lane.
    __builtin_amdgcn_global_load_lds((const AS1 void*)g, (AS3 void*)lds_base, 16, 0, 0);
}

__global__ __launch_bounds__(256, 4)
void fused_dual(const float* __restrict__ x,    // [256,2048]
                const float* __restrict__ fcW,  // [1000,2048]
                const float* __restrict__ fcb,  // [1000]
                const float* __restrict__ W1,   // [4096,2048,4]
                const float* __restrict__ b1,   // [4096,4]
                const float* __restrict__ W2,   // [4096,4]
                const float* __restrict__ b2,   // [4096]
                float* __restrict__ out)        // x1[256*1000] ++ x2[256*4096]
{
    __shared__ __align__(16) char lA[16 * SLAB];   // 16640 B
    __shared__ __align__(16) char lB[16 * SLAB];   // 16640 B
    AS3 char* lA3 = (AS3 char*)lA;
    AS3 char* lB3 = (AS3 char*)lB;

    const int tid  = threadIdx.x;
    const int lane = tid & 63, w = tid >> 6;
    const int l15  = lane & 15, quad = lane >> 4;

    // XCD swizzle: 136 consecutive work-ids per XCD -> 4 row-group siblings
    // of each col-group land on the same XCD.
    const int idx = blockIdx.x;
    const int wid = (idx & 7) * 136 + (idx >> 3);
    const int cg = wid >> 2, rg = wid & 3, m0 = rg * 64;
    const bool is_fc = (cg < 16);
    const int c0 = (is_fc ? cg : cg - 16) * 64;

    // ---- DMA global bases (per lane) ----
    // A: slab q holds block rows 4*(w*4+q)..+3 ; lane -> row (lane>>4), kpart lane&15
    const float* aG = x + (m0 + w * 16 + (lane >> 4)) * 2048 + (lane & 15) * 4;
    // B decoder: slab q = o_local w*4+q ; 1KB contiguous = [64k][4h] fp32
    const float* bG = W1 + ((c0 >> 2) + w * 4) * 8192 + lane * 4;
    // B fc: like A but rows clamped to 999 (cols >=1000 guarded at store)
    const float* bF0; const float* bF1; const float* bF2; const float* bF3;
    {
        int r0 = c0 + w * 16 + (lane >> 4);
        int ra = r0;      if (ra > 999) ra = 999;
        int rb = r0 + 4;  if (rb > 999) rb = 999;
        int rc = r0 + 8;  if (rc > 999) rc = 999;
        int rd = r0 + 12; if (rd > 999) rd = 999;
        bF0 = fcW + ra * 2048 + (lane & 15) * 4;
        bF1 = fcW + rb * 2048 + (lane & 15) * 4;
        bF2 = fcW + rc * 2048 + (lane & 15) * 4;
        bF3 = fcW + rd * 2048 + (lane & 15) * 4;
    }

    const int mt0 = (w >> 1) * 2, nt0 = (w & 1) * 2;   // 2x2 wave tiling

    f32x4 acc[2][2];
    acc[0][0] = acc[0][1] = acc[1][0] = acc[1][1] = (f32x4){0.f, 0.f, 0.f, 0.f};

    for (int kt = 0; kt < 32; ++kt) {
        __syncthreads();                       // all waves done reading prev tile
        // ---- issue DMA for tile kt (8 instrs/wave, drained at next barrier) ----
        const int ka = kt * 64;                // floats
        #pragma unroll
        for (int q = 0; q < 4; ++q)
            dma16(aG + q * 8192 + ka, lA3 + (w * 4 + q) * SLAB);
        if (is_fc) {
            dma16(bF0 + ka, lB3 + (w * 4 + 0) * SLAB);
            dma16(bF1 + ka, lB3 + (w * 4 + 1) * SLAB);
            dma16(bF2 + ka, lB3 + (w * 4 + 2) * SLAB);
            dma16(bF3 + ka, lB3 + (w * 4 + 3) * SLAB);
        } else {
            #pragma unroll
            for (int q = 0; q < 4; ++q)
                dma16(bG + q * 8192 + kt * 256, lB3 + (w * 4 + q) * SLAB);
        }
        __syncthreads();                       // vmcnt(0) drain: tile visible

        // ---- fragments (fp32 LDS -> bf16 regs) ----
        bf16x8 af[2][2], bf[2][2];
        #pragma unroll
        for (int i = 0; i < 2; ++i)
        #pragma unroll
        for (int kk = 0; kk < 2; ++kk) {
            const int arow = (mt0 + i) * 16 + l15;
            const char* p = lA + (arow >> 2) * SLAB + (arow & 3) * 256 + kk * 128 + quad * 32;
            f32x4 u0 = *(const f32x4*)p;
            f32x4 u1 = *(const f32x4*)(p + 16);
            #pragma unroll
            for (int c = 0; c < 4; ++c) { af[i][kk][c] = (bf16_t)u0[c]; af[i][kk][4 + c] = (bf16_t)u1[c]; }
        }
        if (is_fc) {
            #pragma unroll
            for (int j = 0; j < 2; ++j)
            #pragma unroll
            for (int kk = 0; kk < 2; ++kk) {
                const int brow = (nt0 + j) * 16 + l15;
                const char* p = lB + (brow >> 2) * SLAB + (brow & 3) * 256 + kk * 128 + quad * 32;
                f32x4 u0 = *(const f32x4*)p;
                f32x4 u1 = *(const f32x4*)(p + 16);
                #pragma unroll
                for (int c = 0; c < 4; ++c) { bf[j][kk][c] = (bf16_t)u0[c]; bf[j][kk][4 + c] = (bf16_t)u1[c]; }
            }
        } else {
            #pragma unroll
            for (int j = 0; j < 2; ++j)
            #pragma unroll
            for (int kk = 0; kk < 2; ++kk) {
                const int n = (nt0 + j) * 16 + l15;            // col in tile
                const char* p = lB + (n >> 2) * SLAB + (n & 3) * 4 + kk * 512 + quad * 128;
                #pragma unroll
                for (int jj = 0; jj < 8; ++jj)
                    bf[j][kk][jj] = (bf16_t)*(const float*)(p + jj * 16);
            }
        }
        #pragma unroll
        for (int kk = 0; kk < 2; ++kk)
        #pragma unroll
        for (int i = 0; i < 2; ++i)
        #pragma unroll
        for (int j = 0; j < 2; ++j)
            acc[i][j] = __builtin_amdgcn_mfma_f32_16x16x32_bf16(af[i][kk], bf[j][kk], acc[i][j], 0, 0, 0);
    }

    // ---- epilogue ----
    if (is_fc) {
        #pragma unroll
        for (int j = 0; j < 2; ++j) {
            const int c = c0 + (nt0 + j) * 16 + l15;
            const bool valid = (c < 1000);
            const float bias = fcb[valid ? c : 999];
            #pragma unroll
            for (int i = 0; i < 2; ++i)
            #pragma unroll
            for (int r = 0; r < 4; ++r)
                if (valid) {
                    const int row = m0 + (mt0 + i) * 16 + quad * 4 + r;
                    out[row * 1000 + c] = acc[i][j][r] + bias;
                }
        }
    } else {
        float* x2 = out + 256 * 1000;
        const int o0 = (cg - 16) * 16;
        __syncthreads();                       // K-loop LDS reads done; reuse lA
        float* xs = (float*)lA;                // [64 rows][16 o] fp32 = 4KB
        #pragma unroll
        for (int j = 0; j < 2; ++j) {
            const int c = c0 + (nt0 + j) * 16 + l15;
            const float b1v = b1[c], w2v = W2[c];
            const int o = c >> 2;
            const float b2v = b2[o];
            #pragma unroll
            for (int i = 0; i < 2; ++i)
            #pragma unroll
            for (int r = 0; r < 4; ++r) {
                float h = acc[i][j][r] + b1v;
                h = (h >= 0.f) ? h : 0.1f * h;          // leaky relu
                float wv = h * w2v;
                wv += __shfl_xor(wv, 1, 64);            // sum decoder's 4 h-cols
                wv += __shfl_xor(wv, 2, 64);
                if ((lane & 3) == 0) {
                    const int row = (mt0 + i) * 16 + quad * 4 + r;   // block-local
                    xs[row * 16 + (o - o0)] = wv + b2v;
                }
            }
        }
        __syncthreads();
        // full-line stores: 4 threads cover one row's 64B
        const int row = tid >> 2, part = tid & 3;
        f32x4 v = *(const f32x4*)(lA + row * 64 + part * 16);
        *(f32x4*)(x2 + (m0 + row) * 4096 + o0 + part * 4) = v;
    }
}

extern "C" void kernel_launch(void* const* d_in, const int* in_sizes, int n_in,
                              void* d_out, int out_size, void* d_ws, size_t ws_size,
                              hipStream_t stream)
{
    (void)in_sizes; (void)n_in; (void)d_ws; (void)ws_size; (void)out_size;
    const float* x   = (const float*)d_in[0];
    const float* fcW = (const float*)d_in[1];
    const float* fcb = (const float*)d_in[2];
    const float* W1  = (const float*)d_in[3];
    const float* b1  = (const float*)d_in[4];
    const float* W2  = (const float*)d_in[5];
    const float* b2  = (const float*)d_in[6];
    fused_dual<<<1088, 256, 0, stream>>>(x, fcW, fcb, W1, b1, W2, b2, (float*)d_out);
}

// Round 5
// 243.021 us; speedup vs baseline: 1.2437x; 1.2437x over previous
//
#include <hip/hip_runtime.h>

// DualModel3 R5: bf16-in-LDS, 32x32x16 MFMA, XOR-swizzled LDS, reg prefetch.
// R4 lesson: LDS pipe was the bottleneck (4.15e7 conflict cycles; fp32 frags
// + scalar b32 gathers + 4-way conflicts ~= 6.5k LDS-cyc/CU/iter). R5 halves
// LDS bytes (bf16), reads frags as b128 only, swizzles banks, and doubles
// MFMA per frag-byte via 32x32 tiles.
//
// GEMM: M=256 x N=17408 (1024 fc + 16384 dec) x K=2048, BM=128 BN=64 BK=64.
// Grid 272 col-groups x 2 row-groups = 544 blocks x 256 thr, XCD-swizzled.
// Wave-tile 64m x 32n (2 tiles of 32x32, acc 2x16 f32). LDS rows = 128 B,
// granule-16B XOR swizzle by (row&7). C/D: col=lane&31,
// row=(reg&3)+8*(reg>>2)+4*(lane>>5)  [m74/m101]. Decoder epilogue: bias +
// leaky-relu + W2 H-reduce via shfl_xor(1,2), LDS-staged full-line stores.

typedef __bf16 bf16_t;
typedef __bf16 bf16x4 __attribute__((ext_vector_type(4)));
typedef __bf16 bf16x8 __attribute__((ext_vector_type(8)));
typedef float  f32x4  __attribute__((ext_vector_type(4)));
typedef float  f32x16 __attribute__((ext_vector_type(16)));

__global__ __launch_bounds__(256, 2)
void fused_dual(const float* __restrict__ x,    // [256,2048]
                const float* __restrict__ fcW,  // [1000,2048]
                const float* __restrict__ fcb,  // [1000]
                const float* __restrict__ W1,   // [4096,2048,4]
                const float* __restrict__ b1,   // [4096,4]
                const float* __restrict__ W2,   // [4096,4]
                const float* __restrict__ b2,   // [4096]
                float* __restrict__ out)        // x1[256*1000] ++ x2[256*4096]
{
    __shared__ __align__(16) char lA[128 * 128];   // 16 KB bf16 A-tile
    __shared__ __align__(16) char lB[64 * 128];    // 8 KB bf16 B-tile

    const int tid  = threadIdx.x;
    const int lane = tid & 63, w = tid >> 6;
    const int l31  = lane & 31, half = lane >> 5;

    // XCD swizzle: 68 consecutive wids per XCD; row-siblings adjacent.
    const int idx = blockIdx.x;
    const int wid = (idx & 7) * 68 + (idx >> 3);
    const int cg  = wid >> 1, rg = wid & 1, m0 = rg * 128;
    const bool is_fc = (cg < 16);
    const int c0  = (is_fc ? cg : cg - 16) * 64;

    // ---- prefetch addressing ----
    const int arow = tid >> 2;          // 0..63
    const int aq   = tid & 3;           // k quarter-of-16
    const float* aBase = x + (m0 + arow) * 2048 + aq * 4;

    const float* bBase;
    if (is_fc) {
        int rowc = c0 + arow; if (rowc > 999) rowc = 999;   // stores guarded
        bBase = fcW + rowc * 2048 + aq * 4;
    } else {
        bBase = W1 + ((c0 >> 2) + w * 4) * 8192 + lane * 4; // o-major, +q*8192
    }

    f32x4 aR[8], bR[4];

    auto LOAD = [&](int kt) {
        const float* ap = aBase + kt * 64;
        #pragma unroll
        for (int j = 0; j < 8; ++j)
            aR[j] = *(const f32x4*)(ap + (j & 1) * (64 * 2048) + (j >> 1) * 16);
        if (is_fc) {
            const float* bp = bBase + kt * 64;
            #pragma unroll
            for (int j = 0; j < 4; ++j) bR[j] = *(const f32x4*)(bp + j * 16);
        } else {
            const float* bp = bBase + kt * 256;      // 1KB contiguous per o
            #pragma unroll
            for (int q = 0; q < 4; ++q) bR[q] = *(const f32x4*)(bp + q * 8192);
        }
    };

    auto STAGE = [&]() {
        #pragma unroll
        for (int j = 0; j < 8; ++j) {
            const int r  = arow + 64 * (j & 1);
            const int kb = aq * 8 + (j >> 1) * 32;          // byte off (=k*2)
            const int ad = r * 128 + (((kb >> 4) ^ (r & 7)) << 4) + (kb & 15);
            bf16x4 v;
            #pragma unroll
            for (int c = 0; c < 4; ++c) v[c] = (bf16_t)aR[j][c];
            *(bf16x4*)(lA + ad) = v;
        }
        if (is_fc) {
            #pragma unroll
            for (int j = 0; j < 4; ++j) {
                const int kb = aq * 8 + j * 32;
                const int ad = arow * 128 + (((kb >> 4) ^ (arow & 7)) << 4) + (kb & 15);
                bf16x4 v;
                #pragma unroll
                for (int c = 0; c < 4; ++c) v[c] = (bf16_t)bR[j][c];
                *(bf16x4*)(lB + ad) = v;
            }
        } else {
            // lane holds W1[o][k=lane][h0..3]; scatter h to rows n=o*4+h
            const int gsub = ((lane >> 3) << 4) + (lane & 7) * 2; // pre-XOR
            #pragma unroll
            for (int q = 0; q < 4; ++q)
            #pragma unroll
            for (int h = 0; h < 4; ++h) {
                const int n = w * 16 + q * 4 + h;
                const int ad = n * 128 + (gsub ^ ((n & 7) << 4));
                *(bf16_t*)(lB + ad) = (bf16_t)bR[q][h];
            }
        }
    };

    const int mh = (w & 1) * 64, nh = (w >> 1) * 32;   // wave tile 64m x 32n
    f32x16 acc[2];
    #pragma unroll
    for (int i = 0; i < 2; ++i)
        #pragma unroll
        for (int r = 0; r < 16; ++r) acc[i][r] = 0.f;

    LOAD(0);
    for (int kt = 0; kt < 32; ++kt) {
        __syncthreads();                  // frag reads of kt-1 done (+vm drain)
        STAGE();
        __syncthreads();                  // tile kt visible
        if (kt != 31) LOAD(kt + 1);       // in flight across frag+MFMA phase
        const int nrow = nh + l31;
        #pragma unroll
        for (int ks = 0; ks < 4; ++ks) {
            const int g = ks * 2 + half;
            bf16x8 bf = *(const bf16x8*)(lB + nrow * 128 + ((g ^ (nrow & 7)) << 4));
            #pragma unroll
            for (int i = 0; i < 2; ++i) {
                const int mrow = mh + i * 32 + l31;
                bf16x8 af = *(const bf16x8*)(lA + mrow * 128 + ((g ^ (mrow & 7)) << 4));
                acc[i] = __builtin_amdgcn_mfma_f32_32x32x16_bf16(af, bf, acc[i], 0, 0, 0);
            }
        }
    }

    // ---- epilogue ----  C/D: col=lane&31, row=(r&3)+8*(r>>2)+4*half
    if (is_fc) {
        const int c = c0 + nh + l31;
        const bool valid = (c < 1000);
        const float bias = fcb[valid ? c : 999];
        #pragma unroll
        for (int i = 0; i < 2; ++i)
        #pragma unroll
        for (int r = 0; r < 16; ++r) {
            if (valid) {
                const int m = m0 + mh + i * 32 + (r & 3) + 8 * (r >> 2) + 4 * half;
                out[m * 1000 + c] = acc[i][r] + bias;
            }
        }
    } else {
        float* x2 = out + 256 * 1000;
        const int d = cg - 16;                    // decoder col-panel
        const int n_glob = c0 + nh + l31;
        const float b1v = b1[n_glob], w2v = W2[n_glob];
        const float b2v = b2[n_glob >> 2];
        __syncthreads();                          // done with lA; reuse as xs
        float* xs = (float*)lA;                   // [128 rows][16 o] fp32
        const int o_loc = (nh + l31) >> 2;
        #pragma unroll
        for (int i = 0; i < 2; ++i)
        #pragma unroll
        for (int r = 0; r < 16; ++r) {
            float h = acc[i][r] + b1v;
            h = (h >= 0.f) ? h : 0.1f * h;        // leaky relu
            float wv = h * w2v;
            wv += __shfl_xor(wv, 1, 64);          // decoder's 4 h-cols
            wv += __shfl_xor(wv, 2, 64);
            if ((lane & 3) == 0) {
                const int row = mh + i * 32 + (r & 3) + 8 * (r >> 2) + 4 * half;
                xs[row * 16 + o_loc] = wv + b2v;
            }
        }
        __syncthreads();
        #pragma unroll
        for (int j = 0; j < 2; ++j) {
            const int row = (tid >> 2) + 64 * j, part = tid & 3;
            f32x4 v = *(const f32x4*)(xs + row * 16 + part * 4);
            *(f32x4*)(x2 + (m0 + row) * 4096 + d * 16 + part * 4) = v;
        }
    }
}

extern "C" void kernel_launch(void* const* d_in, const int* in_sizes, int n_in,
                              void* d_out, int out_size, void* d_ws, size_t ws_size,
                              hipStream_t stream)
{
    (void)in_sizes; (void)n_in; (void)d_ws; (void)ws_size; (void)out_size;
    const float* x   = (const float*)d_in[0];
    const float* fcW = (const float*)d_in[1];
    const float* fcb = (const float*)d_in[2];
    const float* W1  = (const float*)d_in[3];
    const float* b1  = (const float*)d_in[4];
    const float* W2  = (const float*)d_in[5];
    const float* b2  = (const float*)d_in[6];
    fused_dual<<<544, 256, 0, stream>>>(x, fcW, fcb, W1, b1, W2, b2, (float*)d_out);
}